// Round 1
// baseline (20062.375 us; speedup 1.0000x reference)
//
#include <hip/hip_runtime.h>
#include <math.h>

// PointerNetDecoder on MI355X — round 1: correctness-first f32 pipeline.
// Structure: k_init; k_rw (rW = r@w_ref once); 128x { k_gates -> k_q -> k_score }.
// Outputs written as float32 (tour positions exactly representable); if the
// harness reads int32 this shows up as absmax ~1e9 and we flip next round.

namespace {
constexpr int NB  = 512;   // batch
constexpr int S   = 128;   // seq len == #steps
constexpr int H   = 512;   // hidden
constexpr int IN2 = 2;     // input dim
constexpr float INFV = 1e7f;

__device__ __forceinline__ float sigm(float x) { return 1.f / (1.f + expf(-x)); }
} // namespace

// ---------------- init: state buffers (ws is poisoned 0xAA every call) ---------
__global__ void k_init(const float* __restrict__ h0, const float* __restrict__ c0,
                       const float* __restrict__ bos,
                       float* __restrict__ h, float* __restrict__ c,
                       float* __restrict__ prev, float* __restrict__ mask,
                       float* __restrict__ ll) {
  int i = blockIdx.x * blockDim.x + threadIdx.x;
  if (i < NB * H) { h[i] = h0[i]; c[i] = c0[i]; }
  if (i < NB * S) mask[i] = 0.f;
  if (i < NB) { ll[i] = 0.f; prev[2*i] = bos[0]; prev[2*i+1] = bos[1]; }
}

// ---------------- rW = r @ w_ref : [65536,512] x [512,512] --------------------
// BM=64, BN=64, BK=16, 256 threads, 4x4 per thread.
__global__ __launch_bounds__(256) void k_rw(const float* __restrict__ r,
                                            const float* __restrict__ wref,
                                            float* __restrict__ rW) {
  __shared__ float As[16][64];  // [k][m]
  __shared__ float Bs[16][64];  // [k][n]
  const int tid = threadIdx.x;
  const int tx = tid & 15, ty = tid >> 4;
  const int M0 = blockIdx.x * 64, N0 = blockIdx.y * 64;
  float acc[4][4] = {};
  for (int k0 = 0; k0 < H; k0 += 16) {
    {
      int row = tid >> 2, c4 = (tid & 3) * 4;
      float4 a = *(const float4*)&r[(size_t)(M0 + row) * H + k0 + c4];
      As[c4+0][row] = a.x; As[c4+1][row] = a.y; As[c4+2][row] = a.z; As[c4+3][row] = a.w;
    }
    {
      int row = tid >> 4, c4 = (tid & 15) * 4;
      *(float4*)&Bs[row][c4] = *(const float4*)&wref[(size_t)(k0 + row) * H + N0 + c4];
    }
    __syncthreads();
#pragma unroll
    for (int kk = 0; kk < 16; ++kk) {
      float4 a = *(float4*)&As[kk][ty*4];
      float4 b = *(float4*)&Bs[kk][tx*4];
      float av[4] = {a.x,a.y,a.z,a.w}, bv[4] = {b.x,b.y,b.z,b.w};
#pragma unroll
      for (int i = 0; i < 4; ++i) {
#pragma unroll
        for (int j = 0; j < 4; ++j) acc[i][j] += av[i]*bv[j];
      }
    }
    __syncthreads();
  }
#pragma unroll
  for (int i = 0; i < 4; ++i) {
    *(float4*)&rW[(size_t)(M0 + ty*4 + i) * H + N0 + tx*4] =
        make_float4(acc[i][0], acc[i][1], acc[i][2], acc[i][3]);
  }
}

// ---------------- gates + LSTM cell ------------------------------------------
// Block tile: 64 n x 16 j (x 4 gates = 64 gate cols). grid (8, 32), 256 thr.
// Thread: 4 n x (4 gates for one j) -> activation coupling is thread-local.
__global__ __launch_bounds__(256) void k_gates(
    const float* __restrict__ h_in, const float* __restrict__ Whh,
    const float* __restrict__ Wih, const float* __restrict__ bih,
    const float* __restrict__ bhh, const float* __restrict__ prev,
    float* __restrict__ c, float* __restrict__ h_out) {
  __shared__ float Hs[32][64];   // [k][n]
  __shared__ float Ws[32][64];   // [k][j*4+g]
  const int tid = threadIdx.x;
  const int tj = tid & 15, tn = tid >> 4;
  const int n0 = blockIdx.x * 64, j0 = blockIdx.y * 16;
  float acc[4][4] = {};   // [n_local][gate]
  for (int k0 = 0; k0 < H; k0 += 32) {
#pragma unroll
    for (int rep = 0; rep < 2; ++rep) {
      int t = tid + rep * 256;
      int row = t >> 3, c4 = (t & 7) * 4;
      float4 a = *(const float4*)&h_in[(size_t)(n0 + row) * H + k0 + c4];
      Hs[c4+0][row] = a.x; Hs[c4+1][row] = a.y; Hs[c4+2][row] = a.z; Hs[c4+3][row] = a.w;
      int g = row >> 4, jj = row & 15;
      float4 w = *(const float4*)&Whh[(size_t)(g*H + j0 + jj) * H + k0 + c4];
      Ws[c4+0][jj*4+g] = w.x; Ws[c4+1][jj*4+g] = w.y; Ws[c4+2][jj*4+g] = w.z; Ws[c4+3][jj*4+g] = w.w;
    }
    __syncthreads();
#pragma unroll
    for (int kk = 0; kk < 32; ++kk) {
      float4 hv = *(float4*)&Hs[kk][tn*4];
      float4 wv = *(float4*)&Ws[kk][tj*4];
      float hvv[4] = {hv.x,hv.y,hv.z,hv.w}, wvv[4] = {wv.x,wv.y,wv.z,wv.w};
#pragma unroll
      for (int i = 0; i < 4; ++i) {
#pragma unroll
        for (int g = 0; g < 4; ++g) acc[i][g] += hvv[i]*wvv[g];
      }
    }
    __syncthreads();
  }
  const int j = j0 + tj;
#pragma unroll
  for (int i = 0; i < 4; ++i) {
    int n = n0 + tn*4 + i;
    float p0 = prev[2*n], p1 = prev[2*n+1];
    float gv[4];
#pragma unroll
    for (int g = 0; g < 4; ++g) {
      int m = g*H + j;
      gv[g] = acc[i][g] + bih[m] + bhh[m] + p0*Wih[2*m] + p1*Wih[2*m+1];
    }
    // gate order i,f,g,o
    float cv = c[(size_t)n*H + j];
    float cn = sigm(gv[1])*cv + sigm(gv[0])*tanhf(gv[2]);
    float hn = sigm(gv[3])*tanhf(cn);
    c[(size_t)n*H + j] = cn;
    h_out[(size_t)n*H + j] = hn;
  }
}

// ---------------- q = h_new @ w_q : [512,512]x[512,512] -----------------------
// BM=32, BN=64, BK=32. grid (16, 8), 256 thr, 2x4 per thread.
__global__ __launch_bounds__(256) void k_q(const float* __restrict__ hn,
                                           const float* __restrict__ wq,
                                           float* __restrict__ q) {
  __shared__ float Hs[32][32];   // [k][n]
  __shared__ float Ws[32][64];   // [k][col]
  const int tid = threadIdx.x;
  const int tx = tid & 15, ty = tid >> 4;
  const int n0 = blockIdx.x * 32, c0 = blockIdx.y * 64;
  float acc[2][4] = {};
  for (int k0 = 0; k0 < H; k0 += 32) {
    {
      int row = tid >> 3, c4 = (tid & 7) * 4;
      float4 a = *(const float4*)&hn[(size_t)(n0 + row) * H + k0 + c4];
      Hs[c4+0][row] = a.x; Hs[c4+1][row] = a.y; Hs[c4+2][row] = a.z; Hs[c4+3][row] = a.w;
    }
#pragma unroll
    for (int rep = 0; rep < 2; ++rep) {
      int t = tid + rep * 256;
      int row = t >> 4, c4 = (t & 15) * 4;
      *(float4*)&Ws[row][c4] = *(const float4*)&wq[(size_t)(k0 + row) * H + c0 + c4];
    }
    __syncthreads();
#pragma unroll
    for (int kk = 0; kk < 32; ++kk) {
      float h0v = Hs[kk][ty*2], h1v = Hs[kk][ty*2+1];
      float4 wv = *(float4*)&Ws[kk][tx*4];
      float wvv[4] = {wv.x,wv.y,wv.z,wv.w};
#pragma unroll
      for (int jj = 0; jj < 4; ++jj) { acc[0][jj] += h0v*wvv[jj]; acc[1][jj] += h1v*wvv[jj]; }
    }
    __syncthreads();
  }
#pragma unroll
  for (int i = 0; i < 2; ++i)
    *(float4*)&q[(size_t)(n0 + ty*2 + i) * H + c0 + tx*4] =
        make_float4(acc[i][0], acc[i][1], acc[i][2], acc[i][3]);
}

// ---------------- score + softmax/argmax + state update -----------------------
// One block per n. 4 waves x 32 s-rows; wave 0 finishes softmax/argmax.
__global__ __launch_bounds__(256) void k_score(
    const float* __restrict__ rW, const float* __restrict__ q,
    const float* __restrict__ v, const float* __restrict__ x,
    float* __restrict__ mask, float* __restrict__ ll,
    float* __restrict__ prev, float* __restrict__ out_tour,
    float* __restrict__ out_ll, int step) {
  __shared__ float qs[H], vs[H], ms[S], sc[S];
  const int n = blockIdx.x, tid = threadIdx.x;
  for (int i = tid; i < H/4; i += 256) {
    *(float4*)&qs[i*4] = *(const float4*)&q[(size_t)n*H + i*4];
    *(float4*)&vs[i*4] = *(const float4*)&v[i*4];
  }
  if (tid < S) ms[tid] = mask[n*S + tid];
  __syncthreads();
  const int wave = tid >> 6, lane = tid & 63;
  for (int s = wave; s < S; s += 4) {
    const float* row = &rW[((size_t)n*S + s) * H];
    float sum = 0.f;
#pragma unroll
    for (int cch = 0; cch < H/64; ++cch) {
      int hh = cch*64 + lane;
      sum += tanhf(row[hh] + qs[hh]) * vs[hh];
    }
#pragma unroll
    for (int off = 32; off > 0; off >>= 1) sum += __shfl_down(sum, off);
    if (lane == 0) sc[s] = sum - INFV * ms[s];
  }
  __syncthreads();
  if (wave == 0) {
    float v0 = sc[lane], v1 = sc[lane + 64];
    float bv; int bi;
    if (v1 > v0) { bv = v1; bi = lane + 64; } else { bv = v0; bi = lane; }
#pragma unroll
    for (int off = 32; off > 0; off >>= 1) {
      float ov = __shfl_down(bv, off);
      int   oi = __shfl_down(bi, off);
      if (ov > bv || (ov == bv && oi < bi)) { bv = ov; bi = oi; }
    }
    bv = __shfl(bv, 0); bi = __shfl(bi, 0);
    float e = expf(sc[lane] - bv) + expf(sc[lane + 64] - bv);
#pragma unroll
    for (int off = 32; off > 0; off >>= 1) e += __shfl_down(e, off);
    if (lane == 0) {
      // logp at argmax = score[pos]-max-log(sumexp) = -log(sumexp)
      float nll = ll[n] - logf(e);
      ll[n] = nll;
      out_ll[n] = nll;
      out_tour[(size_t)n*S + step] = (float)bi;
      mask[n*S + bi] = 1.f;
      prev[2*n]   = x[((size_t)n*S + bi)*IN2 + 0];
      prev[2*n+1] = x[((size_t)n*S + bi)*IN2 + 1];
    }
  }
}

extern "C" void kernel_launch(void* const* d_in, const int* in_sizes, int n_in,
                              void* d_out, int out_size, void* d_ws, size_t ws_size,
                              hipStream_t stream) {
  const float* x    = (const float*)d_in[0];
  const float* r    = (const float*)d_in[1];
  const float* h0   = (const float*)d_in[2];
  const float* c0   = (const float*)d_in[3];
  const float* Wih  = (const float*)d_in[4];
  const float* Whh  = (const float*)d_in[5];
  const float* bih  = (const float*)d_in[6];
  const float* bhh  = (const float*)d_in[7];
  const float* wref = (const float*)d_in[8];
  const float* wq   = (const float*)d_in[9];
  const float* v    = (const float*)d_in[10];
  const float* bos  = (const float*)d_in[11];
  float* out = (float*)d_out;                 // [NB*S tour | NB ll], f32
  float* ws  = (float*)d_ws;

  size_t off = 0;
  float* rW   = ws + off; off += (size_t)NB * S * H;  // 134.2 MB
  float* hb0  = ws + off; off += (size_t)NB * H;
  float* hb1  = ws + off; off += (size_t)NB * H;
  float* c    = ws + off; off += (size_t)NB * H;
  float* q    = ws + off; off += (size_t)NB * H;
  float* prev = ws + off; off += (size_t)NB * 2;
  float* mask = ws + off; off += (size_t)NB * S;
  float* ll   = ws + off; off += (size_t)NB;

  k_init<<<(NB*H + 255)/256, 256, 0, stream>>>(h0, c0, bos, hb0, c, prev, mask, ll);
  k_rw<<<dim3(NB*S/64, H/64), 256, 0, stream>>>(r, wref, rW);

  float* hbuf[2] = {hb0, hb1};
  for (int t = 0; t < S; ++t) {
    float* hi = hbuf[t & 1];
    float* ho = hbuf[(t + 1) & 1];
    k_gates<<<dim3(NB/64, H/16), 256, 0, stream>>>(hi, Whh, Wih, bih, bhh, prev, c, ho);
    k_q<<<dim3(NB/32, H/64), 256, 0, stream>>>(ho, wq, q);
    k_score<<<NB, 256, 0, stream>>>(rW, q, v, x, mask, ll, prev,
                                    out, out + (size_t)NB*S, t);
  }
}